// Round 4
// baseline (378.994 us; speedup 1.0000x reference)
//
#include <hip/hip_runtime.h>
#include <hip/hip_bf16.h>

#define N_NODES 100000
#define N_EDGES 1000000
#define EMB 64
#define HID 64
#define SCAN_B 256
#define N_BLOCKS_SCAN ((N_NODES + SCAN_B - 1) / SCAN_B)   // 391

// histogram partitioning
#define RSIZE  25600          // bins per range
#define RWORDS 12800          // u32 words per range (2 x u16 bins per word)
#define RANGES 4              // 4*25600 = 102400 >= 100000
#define CHUNKS 4
#define CHUNK_SZ (N_EDGES / CHUNKS)

// ---------------- workspace layout (bytes) ----------------
// gcnt_s    [0        ..   204,800)  u32[4*12800]  packed u16 counts (zeroed)
// gcnt_r    [204,800  ..   409,600)  u32[4*12800]  packed u16 counts (zeroed)
// row_start [409,600  ..   809,616)  int[N+1]
// cursor    [809,616  .. 1,209,616)  int[N]
// blockSums [1,209,616.. 1,211,184)  int[391]
// blockOffs [1,211,184.. 1,212,752)  int[391]
// rs        [1,212,752.. 1,612,752)  float[N]   rsqrt(max(send_deg,1))
// col       [1,612,752.. 5,612,752)  int[E]
// agg1      [5,612,752..31,212,752)  float[N*64]
// z         [31,212,752..31,612,752) float[N]
// memset covers [0, 409,600) only.

__device__ __forceinline__ int unpack_cnt(const unsigned* __restrict__ g, int n) {
    return (int)((g[n >> 1] >> ((n & 1) * 16)) & 0xffffu);
}

// LDS-range histogram: grid = 2 arrays * RANGES * CHUNKS blocks, 1024 threads
__global__ void k_hist(const int* __restrict__ senders,
                       const int* __restrict__ receivers,
                       unsigned* __restrict__ gcnt_s,
                       unsigned* __restrict__ gcnt_r) {
    __shared__ unsigned lds[RWORDS];
    int blk   = blockIdx.x;
    int arr   = blk >> 4;        // 0 = senders, 1 = receivers
    int rem   = blk & 15;
    int range = rem >> 2;
    int chunk = rem & 3;
    const int* __restrict__ src = arr ? receivers : senders;
    unsigned* __restrict__ dst  = arr ? gcnt_r : gcnt_s;

    int t = threadIdx.x;
    for (int w = t; w < RWORDS; w += 1024) lds[w] = 0u;
    __syncthreads();

    int base = range * RSIZE;
    int beg  = chunk * CHUNK_SZ;
    int end  = beg + CHUNK_SZ;
    for (int i = beg + t; i < end; i += 1024) {
        int v = src[i];
        unsigned idx = (unsigned)(v - base);
        if (idx < (unsigned)RSIZE) {
            atomicAdd(&lds[idx >> 1], 1u << ((idx & 1) * 16));
        }
    }
    __syncthreads();

    unsigned* __restrict__ gdst = dst + range * RWORDS;
    for (int w = t; w < RWORDS; w += 1024) {
        unsigned v = lds[w];
        if (v) atomicAdd(&gdst[w], v);   // merges 2 bins per transaction
    }
}

// ---- 3-pass exclusive scan of recv counts -> row_start (+ cursor copy) ----
__global__ void k_scanA(const unsigned* __restrict__ gcnt_r, int* __restrict__ blockSums) {
    __shared__ int s[SCAN_B];
    int t = threadIdx.x;
    int idx = blockIdx.x * SCAN_B + t;
    int v = (idx < N_NODES) ? unpack_cnt(gcnt_r, idx) : 0;
    s[t] = v;
    __syncthreads();
    for (int off = 1; off < SCAN_B; off <<= 1) {
        int x = (t >= off) ? s[t - off] : 0;
        __syncthreads();
        s[t] += x;
        __syncthreads();
    }
    if (t == SCAN_B - 1) blockSums[blockIdx.x] = s[t];
}

__global__ void k_scanB(const int* __restrict__ blockSums, int* __restrict__ blockOffs) {
    __shared__ int s[512];
    int t = threadIdx.x;   // 512 threads, 1 block
    int v = (t < N_BLOCKS_SCAN) ? blockSums[t] : 0;
    s[t] = v;
    __syncthreads();
    for (int off = 1; off < 512; off <<= 1) {
        int x = (t >= off) ? s[t - off] : 0;
        __syncthreads();
        s[t] += x;
        __syncthreads();
    }
    if (t < N_BLOCKS_SCAN) blockOffs[t] = s[t] - v;   // exclusive
}

__global__ void k_scanC(const unsigned* __restrict__ gcnt_r, const int* __restrict__ blockOffs,
                        int* __restrict__ row_start, int* __restrict__ cursor) {
    __shared__ int s[SCAN_B];
    int t = threadIdx.x;
    int idx = blockIdx.x * SCAN_B + t;
    int v = (idx < N_NODES) ? unpack_cnt(gcnt_r, idx) : 0;
    s[t] = v;
    __syncthreads();
    for (int off = 1; off < SCAN_B; off <<= 1) {
        int x = (t >= off) ? s[t - off] : 0;
        __syncthreads();
        s[t] += x;
        __syncthreads();
    }
    if (idx < N_NODES) {
        int row = blockOffs[blockIdx.x] + s[t] - v;   // exclusive prefix
        row_start[idx] = row;
        cursor[idx] = row;
    }
    if (blockIdx.x == 0 && t == 0) row_start[N_NODES] = N_EDGES;
}

__global__ void k_fill(const int* __restrict__ senders, const int* __restrict__ receivers,
                       int* __restrict__ cursor, int* __restrict__ col) {
    int i = blockIdx.x * blockDim.x + threadIdx.x;
    if (i < N_EDGES) {
        int r = receivers[i];
        int pos = atomicAdd(&cursor[r], 1);
        col[pos] = senders[i];
    }
}

// rs[n] = rsqrt(max(send_deg[n],1))
__global__ void k_rs(const unsigned* __restrict__ gcnt_s, float* __restrict__ rs) {
    int n = blockIdx.x * blockDim.x + threadIdx.x;
    if (n < N_NODES) {
        rs[n] = rsqrtf(fmaxf((float)unpack_cnt(gcnt_s, n), 1.0f));
    }
}

// wave per node: agg1[n][lane] = rsqrt(max(indeg,1)) * sum_{s in in(n)} emb[s][lane]*rs[s]
__global__ void k_agg1(const int* __restrict__ row_start,
                       const int* __restrict__ col,
                       const float* __restrict__ rs,
                       const float* __restrict__ emb,
                       float* __restrict__ agg1) {
    int gtid = blockIdx.x * blockDim.x + threadIdx.x;
    int n    = gtid >> 6;
    int lane = threadIdx.x & 63;
    if (n >= N_NODES) return;
    int start = row_start[n];
    int end   = row_start[n + 1];
    float acc = 0.f;
    int i = start;
    for (; i + 1 < end; i += 2) {
        int s0 = col[i];
        int s1 = col[i + 1];
        float r0 = rs[s0];
        float r1 = rs[s1];
        float v0 = emb[(size_t)s0 * 64 + lane];
        float v1 = emb[(size_t)s1 * 64 + lane];
        acc += v0 * r0 + v1 * r1;
    }
    if (i < end) {
        int s0 = col[i];
        acc += emb[(size_t)s0 * 64 + lane] * rs[s0];
    }
    float deg = (float)(end - start);
    agg1[(size_t)n * 64 + lane] = acc * rsqrtf(fmaxf(deg, 1.0f));
}

// thread per node: z[n] = leaky(agg1[n] @ W1) . W2 + b2
__global__ void k_mlp(const float* __restrict__ agg1,
                      const float* __restrict__ W1,
                      const float* __restrict__ W2,
                      const float* __restrict__ b2,
                      float* __restrict__ z) {
    __shared__ float W1s[64 * 64];
    __shared__ float W2s[64];
    int t = threadIdx.x;
    for (int i = t; i < 64 * 64; i += blockDim.x) W1s[i] = W1[i];
    if (t < 64) W2s[t] = W2[t];
    __syncthreads();

    int n = blockIdx.x * blockDim.x + t;
    if (n >= N_NODES) return;

    float e[64];
    const float4* row = (const float4*)(agg1 + (size_t)n * 64);
#pragma unroll
    for (int q = 0; q < 16; ++q) {
        float4 u = row[q];
        e[q * 4 + 0] = u.x; e[q * 4 + 1] = u.y;
        e[q * 4 + 2] = u.z; e[q * 4 + 3] = u.w;
    }

    float zacc = 0.f;
#pragma unroll 4
    for (int j0 = 0; j0 < 64; j0 += 4) {
        float a0 = 0.f, a1 = 0.f, a2 = 0.f, a3 = 0.f;
#pragma unroll
        for (int k = 0; k < 64; ++k) {
            const float4 w = *(const float4*)&W1s[k * 64 + j0];   // wave-broadcast
            a0 += e[k] * w.x;
            a1 += e[k] * w.y;
            a2 += e[k] * w.z;
            a3 += e[k] * w.w;
        }
        a0 = (a0 > 0.f) ? a0 : 0.01f * a0;
        a1 = (a1 > 0.f) ? a1 : 0.01f * a1;
        a2 = (a2 > 0.f) ? a2 : 0.01f * a2;
        a3 = (a3 > 0.f) ? a3 : 0.01f * a3;
        zacc += a0 * W2s[j0] + a1 * W2s[j0 + 1] + a2 * W2s[j0 + 2] + a3 * W2s[j0 + 3];
    }
    z[n] = zacc + b2[0];
}

// thread per node: out[n] = sigmoid( sum over in-edges z[s] )
__global__ void k_agg2_sigmoid(const int* __restrict__ row_start,
                               const int* __restrict__ col,
                               const float* __restrict__ z,
                               float* __restrict__ out) {
    int n = blockIdx.x * blockDim.x + threadIdx.x;
    if (n >= N_NODES) return;
    int start = row_start[n];
    int end   = row_start[n + 1];
    float acc = 0.f;
    for (int i = start; i < end; ++i) acc += z[col[i]];
    out[n] = 1.0f / (1.0f + expf(-acc));
}

extern "C" void kernel_launch(void* const* d_in, const int* in_sizes, int n_in,
                              void* d_out, int out_size, void* d_ws, size_t ws_size,
                              hipStream_t stream) {
    const int* node_ids   = (const int*)d_in[0];  (void)node_ids; // arange
    const int* senders    = (const int*)d_in[1];
    const int* receivers  = (const int*)d_in[2];
    const float* emb      = (const float*)d_in[3];
    const float* W1       = (const float*)d_in[4];
    const float* W2       = (const float*)d_in[5];
    const float* b2       = (const float*)d_in[6];
    float* out            = (float*)d_out;

    char* ws = (char*)d_ws;
    unsigned* gcnt_s  = (unsigned*)(ws);
    unsigned* gcnt_r  = (unsigned*)(ws + 204800);
    int*   row_start  = (int*)(ws + 409600);
    int*   cursor     = (int*)(ws + 809616);
    int*   blockSums  = (int*)(ws + 1209616);
    int*   blockOffs  = (int*)(ws + 1211184);
    float* rs         = (float*)(ws + 1212752);
    int*   col        = (int*)(ws + 1612752);
    float* agg1       = (float*)(ws + 5612752);
    float* z          = (float*)(ws + 31212752);

    hipMemsetAsync(ws, 0, 409600, stream);   // gcnt_s + gcnt_r

    const int B = 256;
    k_hist<<<2 * RANGES * CHUNKS, 1024, 0, stream>>>(senders, receivers, gcnt_s, gcnt_r);
    k_scanA<<<N_BLOCKS_SCAN, SCAN_B, 0, stream>>>(gcnt_r, blockSums);
    k_scanB<<<1, 512, 0, stream>>>(blockSums, blockOffs);
    k_scanC<<<N_BLOCKS_SCAN, SCAN_B, 0, stream>>>(gcnt_r, blockOffs, row_start, cursor);
    k_fill<<<(N_EDGES + B - 1) / B, B, 0, stream>>>(senders, receivers, cursor, col);
    k_rs<<<(N_NODES + B - 1) / B, B, 0, stream>>>(gcnt_s, rs);
    k_agg1<<<(N_NODES * 64 + B - 1) / B, B, 0, stream>>>(row_start, col, rs, emb, agg1);
    k_mlp<<<(N_NODES + B - 1) / B, B, 0, stream>>>(agg1, W1, W2, b2, z);
    k_agg2_sigmoid<<<(N_NODES + B - 1) / B, B, 0, stream>>>(row_start, col, z, out);
}

// Round 5
// 300.416 us; speedup vs baseline: 1.2616x; 1.2616x over previous
//
#include <hip/hip_runtime.h>
#include <hip/hip_bf16.h>

#define N_NODES 100000
#define N_EDGES 1000000
#define EMB 64
#define HID 64
#define SCAN_B 256
#define N_BLOCKS_SCAN ((N_NODES + SCAN_B - 1) / SCAN_B)   // 391

// ---------------- workspace layout (bytes) ----------------
// cnt_s     [0         ..   400,000)  int   (zeroed)
// cnt_r     [400,000   ..   800,000)  int   (zeroed)
// rank      [800,000   .. 4,800,000)  int[E]
// row_start [4,800,000 .. 5,200,016)  int[N+1]
// blockSums [5,200,016 .. 5,201,600)  int[391]
// blockOffs [5,201,600 .. 5,203,200)  int[391]
// rs        [5,203,200 .. 5,603,200)  float[N]   rsqrt(max(send_deg,1))
// col       [5,603,200 .. 9,603,200)  int[E]
// agg1      [9,603,200 ..35,203,200)  float[N*64]
// z         [35,203,200..35,603,200)  float[N]
// memset covers [0, 800,000) only.

// One pass: per-edge rank within its receiver row + sender out-degree count.
__global__ void k_count_rank(const int* __restrict__ senders,
                             const int* __restrict__ receivers,
                             int* __restrict__ cnt_s, int* __restrict__ cnt_r,
                             int* __restrict__ rank) {
    int i = blockIdx.x * blockDim.x + threadIdx.x;
    if (i < N_EDGES) {
        int r = receivers[i];
        int s = senders[i];
        rank[i] = atomicAdd(&cnt_r[r], 1);
        atomicAdd(&cnt_s[s], 1);
    }
}

// ---- 3-pass exclusive scan of cnt_r -> row_start ----
__global__ void k_scanA(const int* __restrict__ cnt_r, int* __restrict__ blockSums) {
    __shared__ int s[SCAN_B];
    int t = threadIdx.x;
    int idx = blockIdx.x * SCAN_B + t;
    int v = (idx < N_NODES) ? cnt_r[idx] : 0;
    s[t] = v;
    __syncthreads();
    for (int off = 1; off < SCAN_B; off <<= 1) {
        int x = (t >= off) ? s[t - off] : 0;
        __syncthreads();
        s[t] += x;
        __syncthreads();
    }
    if (t == SCAN_B - 1) blockSums[blockIdx.x] = s[t];
}

__global__ void k_scanB(const int* __restrict__ blockSums, int* __restrict__ blockOffs) {
    __shared__ int s[512];
    int t = threadIdx.x;   // 512 threads, 1 block
    int v = (t < N_BLOCKS_SCAN) ? blockSums[t] : 0;
    s[t] = v;
    __syncthreads();
    for (int off = 1; off < 512; off <<= 1) {
        int x = (t >= off) ? s[t - off] : 0;
        __syncthreads();
        s[t] += x;
        __syncthreads();
    }
    if (t < N_BLOCKS_SCAN) blockOffs[t] = s[t] - v;   // exclusive
}

// also emits rs[] = rsqrt(max(send_deg,1)) and row_start[N]
__global__ void k_scanC(const int* __restrict__ cnt_r, const int* __restrict__ blockOffs,
                        const int* __restrict__ cnt_s,
                        int* __restrict__ row_start, float* __restrict__ rs) {
    __shared__ int s[SCAN_B];
    int t = threadIdx.x;
    int idx = blockIdx.x * SCAN_B + t;
    int v = (idx < N_NODES) ? cnt_r[idx] : 0;
    s[t] = v;
    __syncthreads();
    for (int off = 1; off < SCAN_B; off <<= 1) {
        int x = (t >= off) ? s[t - off] : 0;
        __syncthreads();
        s[t] += x;
        __syncthreads();
    }
    if (idx < N_NODES) {
        row_start[idx] = blockOffs[blockIdx.x] + s[t] - v;   // exclusive prefix
        rs[idx] = rsqrtf(fmaxf((float)cnt_s[idx], 1.0f));
    }
    if (blockIdx.x == 0 && t == 0) row_start[N_NODES] = N_EDGES;
}

// Atomic-free CSR fill using precomputed ranks.
__global__ void k_place(const int* __restrict__ senders, const int* __restrict__ receivers,
                        const int* __restrict__ rank, const int* __restrict__ row_start,
                        int* __restrict__ col) {
    int i = blockIdx.x * blockDim.x + threadIdx.x;
    if (i < N_EDGES) {
        int r = receivers[i];
        col[row_start[r] + rank[i]] = senders[i];
    }
}

// wave per node: agg1[n][lane] = rsqrt(max(indeg,1)) * sum_{s in in(n)} emb[s][lane]*rs[s]
__global__ void k_agg1(const int* __restrict__ row_start,
                       const int* __restrict__ col,
                       const float* __restrict__ rs,
                       const float* __restrict__ emb,
                       float* __restrict__ agg1) {
    int gtid = blockIdx.x * blockDim.x + threadIdx.x;
    int n    = gtid >> 6;
    int lane = threadIdx.x & 63;
    if (n >= N_NODES) return;
    int start = row_start[n];
    int end   = row_start[n + 1];
    float acc = 0.f;
    int i = start;
    for (; i + 1 < end; i += 2) {
        int s0 = col[i];
        int s1 = col[i + 1];
        float r0 = rs[s0];
        float r1 = rs[s1];
        float v0 = emb[(size_t)s0 * 64 + lane];
        float v1 = emb[(size_t)s1 * 64 + lane];
        acc += v0 * r0 + v1 * r1;
    }
    if (i < end) {
        int s0 = col[i];
        acc += emb[(size_t)s0 * 64 + lane] * rs[s0];
    }
    float deg = (float)(end - start);
    agg1[(size_t)n * 64 + lane] = acc * rsqrtf(fmaxf(deg, 1.0f));
}

// wave per node (grid-stride): lane j holds W1[:,j] in regs; e row read via
// wave-uniform scalar loads; z[n] = leaky(e@W1) . W2 + b2
__global__ void k_mlp(const float* __restrict__ agg1,
                      const float* __restrict__ W1,
                      const float* __restrict__ W2,
                      const float* __restrict__ b2,
                      float* __restrict__ z) {
    int lane  = threadIdx.x & 63;
    int wib   = threadIdx.x >> 6;
    int wpb   = blockDim.x >> 6;
    int gwave = blockIdx.x * wpb + wib;
    int nwav  = gridDim.x * wpb;

    // W1 column 'lane' into 64 VGPRs (coalesced across lanes per k)
    float w1c[64];
#pragma unroll
    for (int k = 0; k < 64; ++k) w1c[k] = W1[k * 64 + lane];
    float w2   = W2[lane];
    float bias = b2[0];

    for (int n = gwave; n < N_NODES; n += nwav) {
        int nu = __builtin_amdgcn_readfirstlane(n);   // wave-uniform -> scalar loads
        const float* __restrict__ e = agg1 + (size_t)nu * 64;
        float a0 = 0.f, a1 = 0.f, a2 = 0.f, a3 = 0.f;
#pragma unroll
        for (int k = 0; k < 64; k += 4) {
            a0 += e[k + 0] * w1c[k + 0];
            a1 += e[k + 1] * w1c[k + 1];
            a2 += e[k + 2] * w1c[k + 2];
            a3 += e[k + 3] * w1c[k + 3];
        }
        float a = (a0 + a1) + (a2 + a3);
        a = (a > 0.f) ? a : 0.01f * a;
        float p = a * w2;
#pragma unroll
        for (int off = 32; off > 0; off >>= 1) p += __shfl_xor(p, off, 64);
        if (lane == 0) z[nu] = p + bias;
    }
}

// thread per node: out[n] = sigmoid( sum over in-edges z[s] )
__global__ void k_agg2_sigmoid(const int* __restrict__ row_start,
                               const int* __restrict__ col,
                               const float* __restrict__ z,
                               float* __restrict__ out) {
    int n = blockIdx.x * blockDim.x + threadIdx.x;
    if (n >= N_NODES) return;
    int start = row_start[n];
    int end   = row_start[n + 1];
    float acc = 0.f;
    for (int i = start; i < end; ++i) acc += z[col[i]];
    out[n] = 1.0f / (1.0f + expf(-acc));
}

extern "C" void kernel_launch(void* const* d_in, const int* in_sizes, int n_in,
                              void* d_out, int out_size, void* d_ws, size_t ws_size,
                              hipStream_t stream) {
    const int* node_ids   = (const int*)d_in[0];  (void)node_ids; // arange
    const int* senders    = (const int*)d_in[1];
    const int* receivers  = (const int*)d_in[2];
    const float* emb      = (const float*)d_in[3];
    const float* W1       = (const float*)d_in[4];
    const float* W2       = (const float*)d_in[5];
    const float* b2       = (const float*)d_in[6];
    float* out            = (float*)d_out;

    char* ws = (char*)d_ws;
    int*   cnt_s     = (int*)(ws);
    int*   cnt_r     = (int*)(ws + 400000);
    int*   rank      = (int*)(ws + 800000);
    int*   row_start = (int*)(ws + 4800000);
    int*   blockSums = (int*)(ws + 5200016);
    int*   blockOffs = (int*)(ws + 5201600);
    float* rs        = (float*)(ws + 5203200);
    int*   col       = (int*)(ws + 5603200);
    float* agg1      = (float*)(ws + 9603200);
    float* z         = (float*)(ws + 35203200);

    hipMemsetAsync(ws, 0, 800000, stream);   // cnt_s + cnt_r

    const int B = 256;
    k_count_rank<<<(N_EDGES + B - 1) / B, B, 0, stream>>>(senders, receivers, cnt_s, cnt_r, rank);
    k_scanA<<<N_BLOCKS_SCAN, SCAN_B, 0, stream>>>(cnt_r, blockSums);
    k_scanB<<<1, 512, 0, stream>>>(blockSums, blockOffs);
    k_scanC<<<N_BLOCKS_SCAN, SCAN_B, 0, stream>>>(cnt_r, blockOffs, cnt_s, row_start, rs);
    k_place<<<(N_EDGES + B - 1) / B, B, 0, stream>>>(senders, receivers, rank, row_start, col);
    k_agg1<<<(N_NODES * 64 + B - 1) / B, B, 0, stream>>>(row_start, col, rs, emb, agg1);
    k_mlp<<<1024, 256, 0, stream>>>(agg1, W1, W2, b2, z);
    k_agg2_sigmoid<<<(N_NODES + B - 1) / B, B, 0, stream>>>(row_start, col, z, out);
}

// Round 6
// 285.457 us; speedup vs baseline: 1.3277x; 1.0524x over previous
//
#include <hip/hip_runtime.h>
#include <hip/hip_bf16.h>

#define N_NODES 100000
#define N_EDGES 1000000
#define EMB 64
#define HID 64
#define SCAN_B 256
#define N_BLOCKS_SCAN ((N_NODES + SCAN_B - 1) / SCAN_B)   // 391

// sender-histogram partitioning (no global atomics)
#define RANGES 4
#define RSIZE  25000          // bins per range; 4*25000 = 100000 exactly
#define RWORDS 12500          // u32 words per range (2 x u16 bins per word)
#define CHUNKS 32
#define CHUNK_EDGES (N_EDGES / CHUNKS)   // 31250

// ---------------- workspace layout (bytes) ----------------
// cnt_r     [0         ..   400,000)  int      (zeroed)
// rank      [400,000   .. 4,400,000)  int[E]
// row_start [4,400,000 .. 4,800,016)  int[N+1]
// blockSums [4,800,016 .. 4,801,580)  int[391]
// blockOffs [4,801,600 .. 4,803,164)  int[391]
// rs        [4,803,200 .. 5,203,200)  float[N]  rsqrt(max(send_deg,1))
// ghist     [5,203,200 ..11,603,200)  u32[128*12500] per-(range,chunk) copies
// col       [11,603,200..15,603,200)  int[E]
// z         [15,603,200..16,003,200)  float[N]
// memset covers [0, 400,000) only.

// Sender histogram: block (range r, chunk c) counts its chunk's senders that
// fall in its range into packed-u16 LDS bins, then writes its private copy
// to global with plain coalesced stores. Zero global atomics.
__global__ void k_hist_s(const int* __restrict__ senders,
                         unsigned* __restrict__ ghist) {
    __shared__ unsigned lds[RWORDS];   // 50 KB
    int r = blockIdx.x >> 5;           // 0..3
    int c = blockIdx.x & 31;           // 0..31
    int t = threadIdx.x;

    for (int w = t; w < RWORDS; w += 1024) lds[w] = 0u;
    __syncthreads();

    int base = r * RSIZE;
    int beg  = c * CHUNK_EDGES;
    int end  = beg + CHUNK_EDGES;
    for (int i = beg + t; i < end; i += 1024) {
        unsigned idx = (unsigned)(senders[i] - base);
        if (idx < (unsigned)RSIZE) {
            atomicAdd(&lds[idx >> 1], 1u << ((idx & 1) * 16));  // LDS atomic
        }
    }
    __syncthreads();

    unsigned* __restrict__ dst = ghist + (size_t)blockIdx.x * RWORDS;
    for (int w = t; w < RWORDS; w += 1024) dst[w] = lds[w];
}

// Dense reduce of the 32 chunk-copies per range -> rs[] = rsqrt(max(deg,1)).
// Packed u32 adds are safe: per-node degree << 65536, no cross-half carry.
__global__ void k_reduce_rs(const unsigned* __restrict__ ghist,
                            float* __restrict__ rs) {
    int tid = blockIdx.x * blockDim.x + threadIdx.x;   // word id in [0, 50000)
    if (tid >= RANGES * RWORDS) return;
    int r = tid / RWORDS;
    int w = tid - r * RWORDS;
    const unsigned* __restrict__ base = ghist + (size_t)(r * CHUNKS) * RWORDS + w;
    unsigned sum = 0;
#pragma unroll
    for (int c = 0; c < CHUNKS; ++c) sum += base[(size_t)c * RWORDS];
    int n0 = r * RSIZE + 2 * w;
    float d0 = (float)(sum & 0xffffu);
    float d1 = (float)(sum >> 16);
    rs[n0]     = rsqrtf(fmaxf(d0, 1.0f));
    rs[n0 + 1] = rsqrtf(fmaxf(d1, 1.0f));
}

// 1M atomics: per-edge rank within its receiver row (+ in-degree counts).
__global__ void k_rank(const int* __restrict__ receivers,
                       int* __restrict__ cnt_r, int* __restrict__ rank) {
    int i = blockIdx.x * blockDim.x + threadIdx.x;
    if (i < N_EDGES) {
        rank[i] = atomicAdd(&cnt_r[receivers[i]], 1);
    }
}

// ---- 3-pass exclusive scan of cnt_r -> row_start ----
__global__ void k_scanA(const int* __restrict__ cnt_r, int* __restrict__ blockSums) {
    __shared__ int s[SCAN_B];
    int t = threadIdx.x;
    int idx = blockIdx.x * SCAN_B + t;
    int v = (idx < N_NODES) ? cnt_r[idx] : 0;
    s[t] = v;
    __syncthreads();
    for (int off = 1; off < SCAN_B; off <<= 1) {
        int x = (t >= off) ? s[t - off] : 0;
        __syncthreads();
        s[t] += x;
        __syncthreads();
    }
    if (t == SCAN_B - 1) blockSums[blockIdx.x] = s[t];
}

__global__ void k_scanB(const int* __restrict__ blockSums, int* __restrict__ blockOffs) {
    __shared__ int s[512];
    int t = threadIdx.x;   // 512 threads, 1 block
    int v = (t < N_BLOCKS_SCAN) ? blockSums[t] : 0;
    s[t] = v;
    __syncthreads();
    for (int off = 1; off < 512; off <<= 1) {
        int x = (t >= off) ? s[t - off] : 0;
        __syncthreads();
        s[t] += x;
        __syncthreads();
    }
    if (t < N_BLOCKS_SCAN) blockOffs[t] = s[t] - v;   // exclusive
}

__global__ void k_scanC(const int* __restrict__ cnt_r, const int* __restrict__ blockOffs,
                        int* __restrict__ row_start) {
    __shared__ int s[SCAN_B];
    int t = threadIdx.x;
    int idx = blockIdx.x * SCAN_B + t;
    int v = (idx < N_NODES) ? cnt_r[idx] : 0;
    s[t] = v;
    __syncthreads();
    for (int off = 1; off < SCAN_B; off <<= 1) {
        int x = (t >= off) ? s[t - off] : 0;
        __syncthreads();
        s[t] += x;
        __syncthreads();
    }
    if (idx < N_NODES) row_start[idx] = blockOffs[blockIdx.x] + s[t] - v;
    if (blockIdx.x == 0 && t == 0) row_start[N_NODES] = N_EDGES;
}

// Atomic-free CSR fill using precomputed ranks.
__global__ void k_place(const int* __restrict__ senders, const int* __restrict__ receivers,
                        const int* __restrict__ rank, const int* __restrict__ row_start,
                        int* __restrict__ col) {
    int i = blockIdx.x * blockDim.x + threadIdx.x;
    if (i < N_EDGES) {
        col[row_start[receivers[i]] + rank[i]] = senders[i];
    }
}

// Fused: wave per node (grid-stride).
//   acc[lane] = rsqrt(indeg) * sum_{s in in(n)} emb[s][lane]*rs[s]
//   a[lane]   = (acc @ W1)[lane]  via v_readlane broadcast, W1 col in 64 VGPRs
//   z[n]      = leaky(a) . W2 + b2   via shuffle reduce
__global__ void k_agg1_mlp(const int* __restrict__ row_start,
                           const int* __restrict__ col,
                           const float* __restrict__ rs,
                           const float* __restrict__ emb,
                           const float* __restrict__ W1,
                           const float* __restrict__ W2,
                           const float* __restrict__ b2,
                           float* __restrict__ z) {
    int lane = threadIdx.x & 63;
    int wib  = threadIdx.x >> 6;
    int wpb  = blockDim.x >> 6;
    int gw   = blockIdx.x * wpb + wib;
    int nw   = gridDim.x * wpb;

    // W1 column 'lane' into 64 VGPRs (coalesced per k); loaded once per wave
    float w1c[64];
#pragma unroll
    for (int k = 0; k < 64; ++k) w1c[k] = W1[k * 64 + lane];
    float w2   = W2[lane];
    float bias = b2[0];

    for (int n = gw; n < N_NODES; n += nw) {
        int start = row_start[n];
        int end   = row_start[n + 1];
        float acc = 0.f;
        int i = start;
        for (; i + 1 < end; i += 2) {
            int s0 = col[i];
            int s1 = col[i + 1];
            float r0 = rs[s0];
            float r1 = rs[s1];
            float v0 = emb[(size_t)s0 * 64 + lane];
            float v1 = emb[(size_t)s1 * 64 + lane];
            acc += v0 * r0 + v1 * r1;
        }
        if (i < end) {
            int s0 = col[i];
            acc += emb[(size_t)s0 * 64 + lane] * rs[s0];
        }
        acc *= rsqrtf(fmaxf((float)(end - start), 1.0f));

        // a = (row acc) @ W1, column 'lane': broadcast acc via readlane
        float a = 0.f;
        int acci = __float_as_int(acc);
#pragma unroll
        for (int k = 0; k < 64; ++k) {
            float ek = __int_as_float(__builtin_amdgcn_readlane(acci, k));
            a += ek * w1c[k];
        }
        a = (a > 0.f) ? a : 0.01f * a;
        float p = a * w2;
#pragma unroll
        for (int off = 32; off > 0; off >>= 1) p += __shfl_xor(p, off, 64);
        if (lane == 0) z[n] = p + bias;
    }
}

// thread per node: out[n] = sigmoid( sum over in-edges z[s] )
__global__ void k_agg2_sigmoid(const int* __restrict__ row_start,
                               const int* __restrict__ col,
                               const float* __restrict__ z,
                               float* __restrict__ out) {
    int n = blockIdx.x * blockDim.x + threadIdx.x;
    if (n >= N_NODES) return;
    int start = row_start[n];
    int end   = row_start[n + 1];
    float acc = 0.f;
    int i = start;
    for (; i + 1 < end; i += 2) {
        float a = z[col[i]];
        float b = z[col[i + 1]];
        acc += a + b;
    }
    if (i < end) acc += z[col[i]];
    out[n] = 1.0f / (1.0f + expf(-acc));
}

extern "C" void kernel_launch(void* const* d_in, const int* in_sizes, int n_in,
                              void* d_out, int out_size, void* d_ws, size_t ws_size,
                              hipStream_t stream) {
    const int* node_ids   = (const int*)d_in[0];  (void)node_ids; // arange
    const int* senders    = (const int*)d_in[1];
    const int* receivers  = (const int*)d_in[2];
    const float* emb      = (const float*)d_in[3];
    const float* W1       = (const float*)d_in[4];
    const float* W2       = (const float*)d_in[5];
    const float* b2       = (const float*)d_in[6];
    float* out            = (float*)d_out;

    char* ws = (char*)d_ws;
    int*      cnt_r     = (int*)(ws);
    int*      rank      = (int*)(ws + 400000);
    int*      row_start = (int*)(ws + 4400000);
    int*      blockSums = (int*)(ws + 4800016);
    int*      blockOffs = (int*)(ws + 4801600);
    float*    rs        = (float*)(ws + 4803200);
    unsigned* ghist     = (unsigned*)(ws + 5203200);
    int*      col       = (int*)(ws + 11603200);
    float*    z         = (float*)(ws + 15603200);

    hipMemsetAsync(ws, 0, 400000, stream);   // cnt_r only

    const int B = 256;
    k_hist_s<<<RANGES * CHUNKS, 1024, 0, stream>>>(senders, ghist);
    k_reduce_rs<<<(RANGES * RWORDS + B - 1) / B, B, 0, stream>>>(ghist, rs);
    k_rank<<<(N_EDGES + B - 1) / B, B, 0, stream>>>(receivers, cnt_r, rank);
    k_scanA<<<N_BLOCKS_SCAN, SCAN_B, 0, stream>>>(cnt_r, blockSums);
    k_scanB<<<1, 512, 0, stream>>>(blockSums, blockOffs);
    k_scanC<<<N_BLOCKS_SCAN, SCAN_B, 0, stream>>>(cnt_r, blockOffs, row_start);
    k_place<<<(N_EDGES + B - 1) / B, B, 0, stream>>>(senders, receivers, rank, row_start, col);
    k_agg1_mlp<<<2048, 256, 0, stream>>>(row_start, col, rs, emb, W1, W2, b2, z);
    k_agg2_sigmoid<<<(N_NODES + B - 1) / B, B, 0, stream>>>(row_start, col, z, out);
}

// Round 7
// 265.210 us; speedup vs baseline: 1.4290x; 1.0763x over previous
//
#include <hip/hip_runtime.h>
#include <hip/hip_bf16.h>

#define N_NODES 100000
#define N_EDGES 1000000
#define EMB 64
#define HID 64
#define SCAN_B 256
#define N_BLOCKS_SCAN ((N_NODES + SCAN_B - 1) / SCAN_B)   // 391

// histogram partitioning (no global atomics)
#define RANGES 4
#define RSIZE  25000          // bins per range; 4*25000 = 100000 exactly
#define RWORDS 12500          // u32 words per range (2 x u16 bins per word)
#define CHUNKS 32
#define CHUNK_EDGES (N_EDGES / CHUNKS)   // 31250

// ---------------- workspace layout (bytes) ----------------
// ghist_s   [0         .. 6,400,000)   u32[128*12500] sender per-(range,chunk)
// ghist_r   [6,400,000 ..12,800,000)   u32[128*12500] receiver copies
// cnt_r     [12,800,000..13,200,000)   int[N]
// row_start [13,200,000..13,600,016)   int[N+1]
// cursor    [13,600,016..14,000,016)   int[N]
// blockSums [14,000,016..14,001,584)   int[391]
// blockOffs [14,001,600..14,003,164)   int[391]
// rs        [14,003,200..14,403,200)   float[N]  rsqrt(max(send_deg,1))
// col       [14,403,200..18,403,200)   int[E]
// h         [18,403,200..44,003,200)   float[N*64]
// z         [44,003,200..44,403,200)   float[N]
// NO memset: every buffer is densely overwritten before first read.

// Histogram both index arrays: block (arr a, range r, chunk c) counts its
// chunk's entries falling in its range into packed-u16 LDS bins, then writes
// its private copy densely. Zero global atomics.
__global__ void k_hist(const int* __restrict__ senders,
                       const int* __restrict__ receivers,
                       unsigned* __restrict__ ghist_s,
                       unsigned* __restrict__ ghist_r) {
    __shared__ unsigned lds[RWORDS];   // 50 KB
    int blk = blockIdx.x;              // [0, 256)
    int arr = blk >> 7;                // 0 = senders, 1 = receivers
    int rem = blk & 127;
    int r   = rem >> 5;                // range 0..3
    int c   = rem & 31;                // chunk 0..31
    const int* __restrict__ src = arr ? receivers : senders;
    unsigned* __restrict__ gh   = arr ? ghist_r : ghist_s;
    int t = threadIdx.x;

    for (int w = t; w < RWORDS; w += 1024) lds[w] = 0u;
    __syncthreads();

    int base = r * RSIZE;
    int beg  = c * CHUNK_EDGES;
    int end  = beg + CHUNK_EDGES;
    for (int i = beg + t; i < end; i += 1024) {
        unsigned idx = (unsigned)(src[i] - base);
        if (idx < (unsigned)RSIZE) {
            atomicAdd(&lds[idx >> 1], 1u << ((idx & 1) * 16));  // LDS atomic
        }
    }
    __syncthreads();

    unsigned* __restrict__ dst = gh + (size_t)rem * RWORDS;
    for (int w = t; w < RWORDS; w += 1024) dst[w] = lds[w];
}

// Dense reduce of 32 chunk-copies per (arr, range):
//   senders  -> rs[] = rsqrt(max(deg,1))
//   receivers-> cnt_r[] (int)
// Packed u32 adds safe: per-node degree << 65536.
__global__ void k_reduce(const unsigned* __restrict__ ghist_s,
                         const unsigned* __restrict__ ghist_r,
                         float* __restrict__ rs, int* __restrict__ cnt_r) {
    int tid = blockIdx.x * blockDim.x + threadIdx.x;   // [0, 100000)
    if (tid >= 2 * RANGES * RWORDS) return;
    int arr = tid / (RANGES * RWORDS);
    int rem = tid - arr * (RANGES * RWORDS);
    int r = rem / RWORDS;
    int w = rem - r * RWORDS;
    const unsigned* __restrict__ gh = arr ? ghist_r : ghist_s;
    const unsigned* __restrict__ base = gh + (size_t)(r * CHUNKS) * RWORDS + w;
    unsigned sum = 0;
#pragma unroll
    for (int c = 0; c < CHUNKS; ++c) sum += base[(size_t)c * RWORDS];
    int n0 = r * RSIZE + 2 * w;
    if (arr == 0) {
        rs[n0]     = rsqrtf(fmaxf((float)(sum & 0xffffu), 1.0f));
        rs[n0 + 1] = rsqrtf(fmaxf((float)(sum >> 16), 1.0f));
    } else {
        cnt_r[n0]     = (int)(sum & 0xffffu);
        cnt_r[n0 + 1] = (int)(sum >> 16);
    }
}

// ---- 3-pass exclusive scan of cnt_r -> row_start (+ cursor copy) ----
__global__ void k_scanA(const int* __restrict__ cnt_r, int* __restrict__ blockSums) {
    __shared__ int s[SCAN_B];
    int t = threadIdx.x;
    int idx = blockIdx.x * SCAN_B + t;
    int v = (idx < N_NODES) ? cnt_r[idx] : 0;
    s[t] = v;
    __syncthreads();
    for (int off = 1; off < SCAN_B; off <<= 1) {
        int x = (t >= off) ? s[t - off] : 0;
        __syncthreads();
        s[t] += x;
        __syncthreads();
    }
    if (t == SCAN_B - 1) blockSums[blockIdx.x] = s[t];
}

__global__ void k_scanB(const int* __restrict__ blockSums, int* __restrict__ blockOffs) {
    __shared__ int s[512];
    int t = threadIdx.x;   // 512 threads, 1 block
    int v = (t < N_BLOCKS_SCAN) ? blockSums[t] : 0;
    s[t] = v;
    __syncthreads();
    for (int off = 1; off < 512; off <<= 1) {
        int x = (t >= off) ? s[t - off] : 0;
        __syncthreads();
        s[t] += x;
        __syncthreads();
    }
    if (t < N_BLOCKS_SCAN) blockOffs[t] = s[t] - v;   // exclusive
}

__global__ void k_scanC(const int* __restrict__ cnt_r, const int* __restrict__ blockOffs,
                        int* __restrict__ row_start, int* __restrict__ cursor) {
    __shared__ int s[SCAN_B];
    int t = threadIdx.x;
    int idx = blockIdx.x * SCAN_B + t;
    int v = (idx < N_NODES) ? cnt_r[idx] : 0;
    s[t] = v;
    __syncthreads();
    for (int off = 1; off < SCAN_B; off <<= 1) {
        int x = (t >= off) ? s[t - off] : 0;
        __syncthreads();
        s[t] += x;
        __syncthreads();
    }
    if (idx < N_NODES) {
        int row = blockOffs[blockIdx.x] + s[t] - v;   // exclusive prefix
        row_start[idx] = row;
        cursor[idx] = row;
    }
    if (blockIdx.x == 0 && t == 0) row_start[N_NODES] = N_EDGES;
}

// rank+place fused: 1M cursor atomics + scattered col writes.
__global__ void k_fill(const int* __restrict__ senders, const int* __restrict__ receivers,
                       int* __restrict__ cursor, int* __restrict__ col) {
    int i = blockIdx.x * blockDim.x + threadIdx.x;
    if (i < N_EDGES) {
        int pos = atomicAdd(&cursor[receivers[i]], 1);
        col[pos] = senders[i];
    }
}

// Dense: h[n][lane] = ((emb[n]*rs[n]) @ W1)[lane]
// wave per node (grid-stride); W1 column 'lane' in 64 VGPRs; readlane matvec.
__global__ void k_h(const float* __restrict__ emb,
                    const float* __restrict__ rs,
                    const float* __restrict__ W1,
                    float* __restrict__ h) {
    int lane = threadIdx.x & 63;
    int wib  = threadIdx.x >> 6;
    int wpb  = blockDim.x >> 6;
    int gw   = blockIdx.x * wpb + wib;
    int nw   = gridDim.x * wpb;

    float w1c[64];
#pragma unroll
    for (int k = 0; k < 64; ++k) w1c[k] = W1[k * 64 + lane];

    for (int n = gw; n < N_NODES; n += nw) {
        float e = emb[(size_t)n * 64 + lane] * rs[n];   // rs[n] wave-uniform
        float a = 0.f;
        int ei = __float_as_int(e);
#pragma unroll
        for (int k = 0; k < 64; ++k) {
            a += __int_as_float(__builtin_amdgcn_readlane(ei, k)) * w1c[k];
        }
        h[(size_t)n * 64 + lane] = a;
    }
}

// Pure gather + epilogue: wave per node.
//   acc[lane] = sum_{s in in(n)} h[s][lane]
//   x = acc * rsqrt(max(indeg,1)); leaky; z[n] = x . W2 + b2
__global__ void k_agg_post(const int* __restrict__ row_start,
                           const int* __restrict__ col,
                           const float* __restrict__ h,
                           const float* __restrict__ W2,
                           const float* __restrict__ b2,
                           float* __restrict__ z) {
    int gtid = blockIdx.x * blockDim.x + threadIdx.x;
    int n    = gtid >> 6;
    int lane = threadIdx.x & 63;
    if (n >= N_NODES) return;
    int start = row_start[n];
    int end   = row_start[n + 1];
    float acc = 0.f;
    int i = start;
    for (; i + 3 < end; i += 4) {          // 4 gathers in flight
        int s0 = col[i], s1 = col[i + 1], s2 = col[i + 2], s3 = col[i + 3];
        float v0 = h[(size_t)s0 * 64 + lane];
        float v1 = h[(size_t)s1 * 64 + lane];
        float v2 = h[(size_t)s2 * 64 + lane];
        float v3 = h[(size_t)s3 * 64 + lane];
        acc += (v0 + v1) + (v2 + v3);
    }
    for (; i < end; ++i) acc += h[(size_t)col[i] * 64 + lane];

    float x = acc * rsqrtf(fmaxf((float)(end - start), 1.0f));
    x = (x > 0.f) ? x : 0.01f * x;
    float p = x * W2[lane];
#pragma unroll
    for (int off = 32; off > 0; off >>= 1) p += __shfl_xor(p, off, 64);
    if (lane == 0) z[n] = p + b2[0];
}

// thread per node: out[n] = sigmoid( sum over in-edges z[s] )  (z L2-resident)
__global__ void k_agg2_sigmoid(const int* __restrict__ row_start,
                               const int* __restrict__ col,
                               const float* __restrict__ z,
                               float* __restrict__ out) {
    int n = blockIdx.x * blockDim.x + threadIdx.x;
    if (n >= N_NODES) return;
    int start = row_start[n];
    int end   = row_start[n + 1];
    float acc = 0.f;
    int i = start;
    for (; i + 3 < end; i += 4) {
        float a = z[col[i]], b = z[col[i + 1]];
        float c = z[col[i + 2]], d = z[col[i + 3]];
        acc += (a + b) + (c + d);
    }
    for (; i < end; ++i) acc += z[col[i]];
    out[n] = 1.0f / (1.0f + expf(-acc));
}

extern "C" void kernel_launch(void* const* d_in, const int* in_sizes, int n_in,
                              void* d_out, int out_size, void* d_ws, size_t ws_size,
                              hipStream_t stream) {
    const int* node_ids   = (const int*)d_in[0];  (void)node_ids; // arange
    const int* senders    = (const int*)d_in[1];
    const int* receivers  = (const int*)d_in[2];
    const float* emb      = (const float*)d_in[3];
    const float* W1       = (const float*)d_in[4];
    const float* W2       = (const float*)d_in[5];
    const float* b2       = (const float*)d_in[6];
    float* out            = (float*)d_out;

    char* ws = (char*)d_ws;
    unsigned* ghist_s   = (unsigned*)(ws);
    unsigned* ghist_r   = (unsigned*)(ws + 6400000);
    int*      cnt_r     = (int*)(ws + 12800000);
    int*      row_start = (int*)(ws + 13200000);
    int*      cursor    = (int*)(ws + 13600016);
    int*      blockSums = (int*)(ws + 14000016);
    int*      blockOffs = (int*)(ws + 14001600);
    float*    rs        = (float*)(ws + 14003200);
    int*      col       = (int*)(ws + 14403200);
    float*    h         = (float*)(ws + 18403200);
    float*    z         = (float*)(ws + 44003200);

    const int B = 256;
    k_hist<<<2 * RANGES * CHUNKS * 2, 1024, 0, stream>>>(senders, receivers, ghist_s, ghist_r);
    k_reduce<<<(2 * RANGES * RWORDS + B - 1) / B, B, 0, stream>>>(ghist_s, ghist_r, rs, cnt_r);
    k_scanA<<<N_BLOCKS_SCAN, SCAN_B, 0, stream>>>(cnt_r, blockSums);
    k_scanB<<<1, 512, 0, stream>>>(blockSums, blockOffs);
    k_scanC<<<N_BLOCKS_SCAN, SCAN_B, 0, stream>>>(cnt_r, blockOffs, row_start, cursor);
    k_fill<<<(N_EDGES + B - 1) / B, B, 0, stream>>>(senders, receivers, cursor, col);
    k_h<<<2048, 256, 0, stream>>>(emb, rs, W1, h);
    k_agg_post<<<(N_NODES * 64 + B - 1) / B, B, 0, stream>>>(row_start, col, h, W2, b2, z);
    k_agg2_sigmoid<<<(N_NODES + B - 1) / B, B, 0, stream>>>(row_start, col, z, out);
}

// Round 8
// 229.039 us; speedup vs baseline: 1.6547x; 1.1579x over previous
//
#include <hip/hip_runtime.h>
#include <hip/hip_bf16.h>

#define N_NODES 100000
#define N_EDGES 1000000
#define EMB 64
#define HID 64
#define SCAN_B 256
#define N_BLOCKS_SCAN ((N_NODES + SCAN_B - 1) / SCAN_B)   // 391

// histogram partitioning (no global atomics anywhere)
#define RANGES 4
#define RSIZE  25000          // bins per range; 4*25000 = 100000 exactly
#define RWORDS 12500          // u32 words per range (2 x u16 bins per word)
#define CHUNKS 32
#define CHUNK_EDGES (N_EDGES / CHUNKS)   // 31250

// ---------------- workspace layout (bytes) ----------------
// ghist_s   [0         .. 6,400,000)   u32[128*12500]
// ghist_r   [6,400,000 ..12,800,000)   u32[128*12500]
// coff      [12,800,000..25,600,000)   int[128*25000] per-(range,chunk,bin) base
// cnt_r     [25,600,000..26,000,000)   int[N]
// row_start [26,000,000..26,400,016)   int[N+1]
// blockSums [26,400,016..26,401,580)   int[391]
// blockOffs [26,401,600..26,403,164)   int[391]
// rs        [26,403,200..26,803,200)   float[N]  rsqrt(max(send_deg,1))
// col       [26,803,200..30,803,200)   int[E]
// h16       [30,803,200..43,603,200)   ushort[N*64]  bf16
// z         [43,603,200..44,003,200)   float[N]
// NO memset: every buffer is densely overwritten before first read.

__device__ __forceinline__ unsigned f32_to_bf16(float v) {
    unsigned u = __float_as_uint(v);
    return (u + 0x7fffu + ((u >> 16) & 1u)) >> 16;     // RNE
}
__device__ __forceinline__ float bf16_to_f32(unsigned b) {
    return __uint_as_float(b << 16);
}

// Histogram both index arrays into per-(arr,range,chunk) private copies.
__global__ void k_hist(const int* __restrict__ senders,
                       const int* __restrict__ receivers,
                       unsigned* __restrict__ ghist_s,
                       unsigned* __restrict__ ghist_r) {
    __shared__ unsigned lds[RWORDS];   // 50 KB
    int blk = blockIdx.x;              // [0, 256)
    int arr = blk >> 7;                // 0 = senders, 1 = receivers
    int rem = blk & 127;
    int r   = rem >> 5;                // range 0..3
    int c   = rem & 31;                // chunk 0..31
    const int* __restrict__ src = arr ? receivers : senders;
    unsigned* __restrict__ gh   = arr ? ghist_r : ghist_s;
    int t = threadIdx.x;

    for (int w = t; w < RWORDS; w += 1024) lds[w] = 0u;
    __syncthreads();

    int base = r * RSIZE;
    int beg  = c * CHUNK_EDGES;
    int end  = beg + CHUNK_EDGES;
    for (int i = beg + t; i < end; i += 1024) {
        unsigned idx = (unsigned)(src[i] - base);
        if (idx < (unsigned)RSIZE) {
            atomicAdd(&lds[idx >> 1], 1u << ((idx & 1) * 16));  // LDS atomic
        }
    }
    __syncthreads();

    unsigned* __restrict__ dst = gh + (size_t)rem * RWORDS;
    for (int w = t; w < RWORDS; w += 1024) dst[w] = lds[w];
}

// Dense reduce: senders -> rs[]; receivers -> cnt_r[].
__global__ void k_reduce(const unsigned* __restrict__ ghist_s,
                         const unsigned* __restrict__ ghist_r,
                         float* __restrict__ rs, int* __restrict__ cnt_r) {
    int tid = blockIdx.x * blockDim.x + threadIdx.x;
    if (tid >= 2 * RANGES * RWORDS) return;
    int arr = tid / (RANGES * RWORDS);
    int rem = tid - arr * (RANGES * RWORDS);
    int r = rem / RWORDS;
    int w = rem - r * RWORDS;
    const unsigned* __restrict__ gh = arr ? ghist_r : ghist_s;
    const unsigned* __restrict__ base = gh + (size_t)(r * CHUNKS) * RWORDS + w;
    unsigned sum = 0;
#pragma unroll
    for (int c = 0; c < CHUNKS; ++c) sum += base[(size_t)c * RWORDS];
    int n0 = r * RSIZE + 2 * w;
    if (arr == 0) {
        rs[n0]     = rsqrtf(fmaxf((float)(sum & 0xffffu), 1.0f));
        rs[n0 + 1] = rsqrtf(fmaxf((float)(sum >> 16), 1.0f));
    } else {
        cnt_r[n0]     = (int)(sum & 0xffffu);
        cnt_r[n0 + 1] = (int)(sum >> 16);
    }
}

// ---- 3-pass exclusive scan of cnt_r -> row_start ----
__global__ void k_scanA(const int* __restrict__ cnt_r, int* __restrict__ blockSums) {
    __shared__ int s[SCAN_B];
    int t = threadIdx.x;
    int idx = blockIdx.x * SCAN_B + t;
    int v = (idx < N_NODES) ? cnt_r[idx] : 0;
    s[t] = v;
    __syncthreads();
    for (int off = 1; off < SCAN_B; off <<= 1) {
        int x = (t >= off) ? s[t - off] : 0;
        __syncthreads();
        s[t] += x;
        __syncthreads();
    }
    if (t == SCAN_B - 1) blockSums[blockIdx.x] = s[t];
}

__global__ void k_scanB(const int* __restrict__ blockSums, int* __restrict__ blockOffs) {
    __shared__ int s[512];
    int t = threadIdx.x;   // 512 threads, 1 block
    int v = (t < N_BLOCKS_SCAN) ? blockSums[t] : 0;
    s[t] = v;
    __syncthreads();
    for (int off = 1; off < 512; off <<= 1) {
        int x = (t >= off) ? s[t - off] : 0;
        __syncthreads();
        s[t] += x;
        __syncthreads();
    }
    if (t < N_BLOCKS_SCAN) blockOffs[t] = s[t] - v;   // exclusive
}

__global__ void k_scanC(const int* __restrict__ cnt_r, const int* __restrict__ blockOffs,
                        int* __restrict__ row_start) {
    __shared__ int s[SCAN_B];
    int t = threadIdx.x;
    int idx = blockIdx.x * SCAN_B + t;
    int v = (idx < N_NODES) ? cnt_r[idx] : 0;
    s[t] = v;
    __syncthreads();
    for (int off = 1; off < SCAN_B; off <<= 1) {
        int x = (t >= off) ? s[t - off] : 0;
        __syncthreads();
        s[t] += x;
        __syncthreads();
    }
    if (idx < N_NODES) row_start[idx] = blockOffs[blockIdx.x] + s[t] - v;
    if (blockIdx.x == 0 && t == 0) row_start[N_NODES] = N_EDGES;
}

// Per-(range,chunk,bin) base offsets: coff[r][c][bin] =
//   row_start[node] + sum_{c'<c} ghist_r[r][c'][bin]
__global__ void k_scan_chunks(const unsigned* __restrict__ ghist_r,
                              const int* __restrict__ row_start,
                              int* __restrict__ coff) {
    int tid = blockIdx.x * blockDim.x + threadIdx.x;   // [0, RANGES*RWORDS)
    if (tid >= RANGES * RWORDS) return;
    int r = tid / RWORDS;
    int w = tid - r * RWORDS;
    int n0 = r * RSIZE + 2 * w;
    int run0 = row_start[n0];
    int run1 = row_start[n0 + 1];
    const unsigned* __restrict__ gh = ghist_r + (size_t)(r * CHUNKS) * RWORDS + w;
    int* __restrict__ co = coff + (size_t)(r * CHUNKS) * RSIZE + 2 * w;
#pragma unroll
    for (int c = 0; c < CHUNKS; ++c) {
        unsigned word = gh[(size_t)c * RWORDS];
        co[(size_t)c * RSIZE]     = run0;
        co[(size_t)c * RSIZE + 1] = run1;
        run0 += (int)(word & 0xffffu);
        run1 += (int)(word >> 16);
    }
}

// Atomic-free fill: block (range r, chunk c) recomputes in-chunk ranks via
// packed-u16 LDS atomics (old value = rank) and places with plain stores.
__global__ void k_fill2(const int* __restrict__ senders,
                        const int* __restrict__ receivers,
                        const int* __restrict__ coff,
                        int* __restrict__ col) {
    __shared__ unsigned lds[RWORDS];   // 50 KB
    int r = blockIdx.x >> 5;           // 0..3
    int c = blockIdx.x & 31;           // 0..31
    int t = threadIdx.x;

    for (int w = t; w < RWORDS; w += 1024) lds[w] = 0u;
    __syncthreads();

    int base = r * RSIZE;
    int beg  = c * CHUNK_EDGES;
    int end  = beg + CHUNK_EDGES;
    const int* __restrict__ co = coff + (size_t)(r * CHUNKS + c) * RSIZE;
    for (int i = beg + t; i < end; i += 1024) {
        unsigned idx = (unsigned)(receivers[i] - base);
        if (idx < (unsigned)RSIZE) {
            int sh = (idx & 1) * 16;
            unsigned old = atomicAdd(&lds[idx >> 1], 1u << sh);
            int rank = (int)((old >> sh) & 0xffffu);
            col[co[idx] + rank] = senders[i];
        }
    }
}

// Dense: h16[n][lane] = bf16( ((emb[n]*rs[n]) @ W1)[lane] )
__global__ void k_h(const float* __restrict__ emb,
                    const float* __restrict__ rs,
                    const float* __restrict__ W1,
                    unsigned short* __restrict__ h16) {
    int lane = threadIdx.x & 63;
    int wib  = threadIdx.x >> 6;
    int wpb  = blockDim.x >> 6;
    int gw   = blockIdx.x * wpb + wib;
    int nw   = gridDim.x * wpb;

    float w1c[64];
#pragma unroll
    for (int k = 0; k < 64; ++k) w1c[k] = W1[k * 64 + lane];

    for (int n = gw; n < N_NODES; n += nw) {
        float e = emb[(size_t)n * 64 + lane] * rs[n];   // rs[n] wave-uniform
        float a = 0.f;
        int ei = __float_as_int(e);
#pragma unroll
        for (int k = 0; k < 64; ++k) {
            a += __int_as_float(__builtin_amdgcn_readlane(ei, k)) * w1c[k];
        }
        h16[(size_t)n * 64 + lane] = (unsigned short)f32_to_bf16(a);
    }
}

// Pure gather + epilogue: wave per node, bf16 h (128 B per gathered row).
__global__ void k_agg_post(const int* __restrict__ row_start,
                           const int* __restrict__ col,
                           const unsigned short* __restrict__ h16,
                           const float* __restrict__ W2,
                           const float* __restrict__ b2,
                           float* __restrict__ z) {
    int gtid = blockIdx.x * blockDim.x + threadIdx.x;
    int n    = gtid >> 6;
    int lane = threadIdx.x & 63;
    if (n >= N_NODES) return;
    int start = row_start[n];
    int end   = row_start[n + 1];
    float acc = 0.f;
    int i = start;
    for (; i + 3 < end; i += 4) {          // 4 gathers in flight
        int s0 = col[i], s1 = col[i + 1], s2 = col[i + 2], s3 = col[i + 3];
        float v0 = bf16_to_f32(h16[(size_t)s0 * 64 + lane]);
        float v1 = bf16_to_f32(h16[(size_t)s1 * 64 + lane]);
        float v2 = bf16_to_f32(h16[(size_t)s2 * 64 + lane]);
        float v3 = bf16_to_f32(h16[(size_t)s3 * 64 + lane]);
        acc += (v0 + v1) + (v2 + v3);
    }
    for (; i < end; ++i) acc += bf16_to_f32(h16[(size_t)col[i] * 64 + lane]);

    float x = acc * rsqrtf(fmaxf((float)(end - start), 1.0f));
    x = (x > 0.f) ? x : 0.01f * x;
    float p = x * W2[lane];
#pragma unroll
    for (int off = 32; off > 0; off >>= 1) p += __shfl_xor(p, off, 64);
    if (lane == 0) z[n] = p + b2[0];
}

// thread per node: out[n] = sigmoid( sum over in-edges z[s] )  (z L2-resident)
__global__ void k_agg2_sigmoid(const int* __restrict__ row_start,
                               const int* __restrict__ col,
                               const float* __restrict__ z,
                               float* __restrict__ out) {
    int n = blockIdx.x * blockDim.x + threadIdx.x;
    if (n >= N_NODES) return;
    int start = row_start[n];
    int end   = row_start[n + 1];
    float acc = 0.f;
    int i = start;
    for (; i + 3 < end; i += 4) {
        float a = z[col[i]], b = z[col[i + 1]];
        float c = z[col[i + 2]], d = z[col[i + 3]];
        acc += (a + b) + (c + d);
    }
    for (; i < end; ++i) acc += z[col[i]];
    out[n] = 1.0f / (1.0f + expf(-acc));
}

extern "C" void kernel_launch(void* const* d_in, const int* in_sizes, int n_in,
                              void* d_out, int out_size, void* d_ws, size_t ws_size,
                              hipStream_t stream) {
    const int* node_ids   = (const int*)d_in[0];  (void)node_ids; // arange
    const int* senders    = (const int*)d_in[1];
    const int* receivers  = (const int*)d_in[2];
    const float* emb      = (const float*)d_in[3];
    const float* W1       = (const float*)d_in[4];
    const float* W2       = (const float*)d_in[5];
    const float* b2       = (const float*)d_in[6];
    float* out            = (float*)d_out;

    char* ws = (char*)d_ws;
    unsigned*       ghist_s   = (unsigned*)(ws);
    unsigned*       ghist_r   = (unsigned*)(ws + 6400000);
    int*            coff      = (int*)(ws + 12800000);
    int*            cnt_r     = (int*)(ws + 25600000);
    int*            row_start = (int*)(ws + 26000000);
    int*            blockSums = (int*)(ws + 26400016);
    int*            blockOffs = (int*)(ws + 26401600);
    float*          rs        = (float*)(ws + 26403200);
    int*            col       = (int*)(ws + 26803200);
    unsigned short* h16       = (unsigned short*)(ws + 30803200);
    float*          z         = (float*)(ws + 43603200);

    const int B = 256;
    k_hist<<<2 * RANGES * CHUNKS, 1024, 0, stream>>>(senders, receivers, ghist_s, ghist_r);
    k_reduce<<<(2 * RANGES * RWORDS + B - 1) / B, B, 0, stream>>>(ghist_s, ghist_r, rs, cnt_r);
    k_scanA<<<N_BLOCKS_SCAN, SCAN_B, 0, stream>>>(cnt_r, blockSums);
    k_scanB<<<1, 512, 0, stream>>>(blockSums, blockOffs);
    k_scanC<<<N_BLOCKS_SCAN, SCAN_B, 0, stream>>>(cnt_r, blockOffs, row_start);
    k_scan_chunks<<<(RANGES * RWORDS + B - 1) / B, B, 0, stream>>>(ghist_r, row_start, coff);
    k_fill2<<<RANGES * CHUNKS, 1024, 0, stream>>>(senders, receivers, coff, col);
    k_h<<<2048, 256, 0, stream>>>(emb, rs, W1, h16);
    k_agg_post<<<(N_NODES * 64 + B - 1) / B, B, 0, stream>>>(row_start, col, h16, W2, b2, z);
    k_agg2_sigmoid<<<(N_NODES + B - 1) / B, B, 0, stream>>>(row_start, col, z, out);
}